// Round 17
// baseline (359.156 us; speedup 1.0000x reference)
//
#include <hip/hip_runtime.h>

#define N_NODES 50000
#define N_EDGES 800000
#define K_BR    8
#define N_C     196              // coarse bin: c = d >> 8  (0..195)
#define N_BUK   1568             // bucket b = k*196 + c  (k-major -> branch-pure)
#define CAP_SLOTS 898816         // >= 800000 + 1568*63, multiple of 64
#define MLP_WAVES (CAP_SLOTS/64) // 14044
#define FATB    98               // fat edge blocks: 98*1024*8 = 802816 >= 800000

typedef _Float16 h2 __attribute__((ext_vector_type(2)));
typedef _Float16 half8 __attribute__((ext_vector_type(8)));
typedef float f32x4 __attribute__((ext_vector_type(4)));

#define MFMA(a, b, c) __builtin_amdgcn_mfma_f32_16x16x32_f16((a), (b), (c), 0, 0, 0)

// ---------------- workspace layout (bytes) ----------------
// fbuf      : CAP_SLOTS x 64 B f16      @ 0           (57,524,224)
// payload   : CAP_SLOTS x 16 B          @ 57,524,224  (14,381,056)
// xh        : 50,000 x 32 f16           @ 71,905,280  (3,200,000)
// kcArr     : E u16 (bucket per edge)   @ 75,105,280  (1,600,000)
// bucketCnt : 1568 ints                 @ 76,705,280  (6,272)  [memset 0]
// bucketCur : 1568 ints                 @ 76,711,552  (6,272)  [memset 0]
// slotStart : 1569 ints                 @ 76,717,824  (6,276)
// w1f4      : 2048 uint4 (B-frags L1)   @ 76,724,224  (32,768)
// w2f4      : 1024 uint4 (B-frags L2)   @ 76,756,992  (16,384)
// total: 76,773,376  (< proven ws floor 109,473,920)

__device__ __forceinline__ int branch_idx(float dx, float dy) {
    return (dx > 0.0f ? 1 : 0) + (dy > 0.0f ? 2 : 0) +
           ((fabsf(dx) - fabsf(dy)) > 0.0f ? 4 : 0);
}

__device__ __forceinline__ unsigned pk_f16pair(float a, float b) {
    h2 p; p.x = (_Float16)a; p.y = (_Float16)b;
    return __builtin_bit_cast(unsigned, p);
}

__device__ __forceinline__ unsigned short f16bits(float a) {
    _Float16 h = (_Float16)a;
    return __builtin_bit_cast(unsigned short, h);
}

// Fat histogram pass: LDS 1568-bin hist per block -> ~1559 global atomics per
// block (153K total, vs 800K per-edge: R1/R14-16 proved ~15-19K/us is a hard
// device atomic-throughput floor -> per-edge atomics = 53us; this is ~10us
// hidden under gathers). Also emits bucket id per edge + f16 x-mirror.
__global__ void __launch_bounds__(1024) hist_kernel(
    const int* __restrict__ ei, const float* __restrict__ pos,
    const float* __restrict__ x,
    int* __restrict__ bucketCnt, unsigned short* __restrict__ kcArr,
    unsigned* __restrict__ xh) {
    __shared__ int h[N_BUK];
    int t = threadIdx.x;
    for (int j = t; j < N_BUK; j += 1024) h[j] = 0;
    __syncthreads();
#pragma unroll
    for (int i = 0; i < 8; ++i) {
        int e = blockIdx.x * 8192 + i * 1024 + t;
        if (e < N_EDGES) {
            int s = ei[e], d = ei[N_EDGES + e];
            float2 ps = ((const float2*)pos)[s];
            float2 pd = ((const float2*)pos)[d];
            int k = branch_idx(ps.x - pd.x, ps.y - pd.y);
            int b = k * N_C + (d >> 8);
            atomicAdd(&h[b], 1);
            kcArr[e] = (unsigned short)b;
            float2 xv = ((const float2*)x)[e];   // e covers 800000 float2 = all of x
            xh[e] = pk_f16pair(xv.x, xv.y);
        }
    }
    __syncthreads();
    for (int j = t; j < N_BUK; j += 1024) {
        int c = h[j];
        if (c) atomicAdd(&bucketCnt[j], c);
    }
}

// 64-aligned exclusive scan of bucketCnt -> slotStart[1569] (plain scan of
// align64(cnt) values -> every bucket starts on a wave boundary, so mlp waves
// are bucket-pure). Also packs W1/W2 MFMA B-frags (B[k=quad*8+j][n=lane&15]).
__global__ void __launch_bounds__(1024) tiny_kernel(
    const int* __restrict__ bucketCnt, int* __restrict__ slotStart,
    const float* __restrict__ W1, const float* __restrict__ W2,
    uint4* __restrict__ w1f4, uint4* __restrict__ w2f4) {
    __shared__ int sc[1024];
    int t = threadIdx.x;
    int b0 = 2 * t, b1 = 2 * t + 1;
    int a0 = (b0 < N_BUK) ? ((bucketCnt[b0] + 63) & ~63) : 0;
    int a1 = (b1 < N_BUK) ? ((bucketCnt[b1] + 63) & ~63) : 0;
    sc[t] = a0 + a1;
    __syncthreads();
    for (int off = 1; off < 1024; off <<= 1) {
        int tmp = (t >= off) ? sc[t - off] : 0;
        __syncthreads();
        sc[t] += tmp;
        __syncthreads();
    }
    int excl = sc[t] - (a0 + a1);
    if (b0 < N_BUK) slotStart[b0] = excl;
    if (b1 < N_BUK) slotStart[b1] = excl + a0;
    if (t == 1023) slotStart[N_BUK] = sc[1023];

    for (int idx = t; idx < 3072; idx += 1024) {
        if (idx < 2048) {                         // layer-1 B frags
            int L = idx & 63, fl = idx >> 6;
            int nt = fl & 1, kt = (fl >> 1) & 1, kk = fl >> 2;
            int quad = L >> 4, col = L & 15;
            unsigned dw[4];
#pragma unroll
            for (int i = 0; i < 4; ++i) {
                float v0 = 0.0f, v1 = 0.0f;
                int k0 = kt * 32 + quad * 8 + 2 * i;
                if (k0 < 36)     v0 = W1[kk * 1152 + k0 * 32 + nt * 16 + col];
                if (k0 + 1 < 36) v1 = W1[kk * 1152 + (k0 + 1) * 32 + nt * 16 + col];
                dw[i] = pk_f16pair(v0, v1);
            }
            w1f4[idx] = make_uint4(dw[0], dw[1], dw[2], dw[3]);
        } else {                                  // layer-2 B frags
            int u2 = idx - 2048;
            int L = u2 & 63, fl = u2 >> 6;
            int nt = fl & 1, kk = fl >> 1;
            int quad = L >> 4, col = L & 15;
            unsigned dw[4];
#pragma unroll
            for (int i = 0; i < 4; ++i) {
                int k0 = quad * 8 + 2 * i;
                dw[i] = pk_f16pair(W2[kk * 1024 + k0 * 32 + nt * 16 + col],
                                   W2[kk * 1024 + (k0 + 1) * 32 + nt * 16 + col]);
            }
            w2f4[u2] = make_uint4(dw[0], dw[1], dw[2], dw[3]);
        }
    }
}

// Fat scatter: stash 8 edges in VGPRs, LDS rank (counting pass gives rank),
// claim per-bucket block base (~1559 atomics/block), write 16B payloads
// bucket-dense. No per-edge global atomics anywhere.
__global__ void __launch_bounds__(1024) scatter_kernel(
    const int* __restrict__ ei, const float* __restrict__ ea,
    const float* __restrict__ ew, const unsigned short* __restrict__ kcArr,
    const int* __restrict__ slotStart, int* __restrict__ bucketCur,
    uint4* __restrict__ payload) {
    __shared__ int h[N_BUK];
    __shared__ int base[N_BUK];
    int t = threadIdx.x;
    for (int j = t; j < N_BUK; j += 1024) h[j] = 0;
    __syncthreads();
    unsigned sd[8], brk[8], e01[8], e23[8], ewh[8];
#pragma unroll
    for (int i = 0; i < 8; ++i) {
        int e = blockIdx.x * 8192 + i * 1024 + t;
        bool v = e < N_EDGES;
        int b = 0, rk = 0;
        if (v) {
            int s = ei[e], d = ei[N_EDGES + e];
            sd[i] = (unsigned)s | ((unsigned)d << 16);
            b = kcArr[e];
            rk = atomicAdd(&h[b], 1);
            float4 eav = ((const float4*)ea)[e];
            e01[i] = pk_f16pair(eav.x, eav.y);
            e23[i] = pk_f16pair(eav.z, eav.w);
            ewh[i] = (unsigned)f16bits(ew[e]);
        }
        brk[i] = (unsigned)b | ((unsigned)rk << 16) | (v ? 0x80000000u : 0u);
    }
    __syncthreads();
    for (int j = t; j < N_BUK; j += 1024) {
        int c = h[j];
        base[j] = c ? atomicAdd(&bucketCur[j], c) : 0;
    }
    __syncthreads();
#pragma unroll
    for (int i = 0; i < 8; ++i) {
        if (brk[i] & 0x80000000u) {
            int b = (int)(brk[i] & 0xFFFFu);
            int rk = (int)((brk[i] >> 16) & 0x7FFFu);
            int slot = slotStart[b] + base[b] + rk;
            payload[slot] = make_uint4(sd[i], ewh[i] << 16, e01[i], e23[i]);
        }
    }
}

// MFMA MLP (R12-verified layouts, R14 64-thr single-wave blocks). R17: bucket
// id via wave-uniform binary search over slotStart (64-aligned buckets ->
// waves never straddle); fbuf store at OWN slot = fully coalesced 4KB/wave;
// no nodeStart/slot gathers at all.
__global__ void __launch_bounds__(64) mlp_kernel(
    const uint4* __restrict__ payload,
    const unsigned* __restrict__ xh,
    const uint4* __restrict__ w1f4, const float* __restrict__ b1,
    const uint4* __restrict__ w2f4, const float* __restrict__ b2,
    const int* __restrict__ slotStart, const int* __restrict__ bucketCnt,
    unsigned short* __restrict__ fbuf) {
    __shared__ uint4 lds4[656];   // m 64x144B + h 16x80B = 10,496 B
    char* mreg = (char*)lds4;
    char* hreg = mreg + 9216;

    int u = __builtin_amdgcn_readfirstlane((int)blockIdx.x * 64);
    if (u >= slotStart[N_BUK]) return;
    int lo = 0;
#pragma unroll
    for (int st = 1024; st; st >>= 1) {
        int cand = lo + st;
        if (cand < N_BUK && slotStart[cand] <= u) lo = cand;
    }
    int b = __builtin_amdgcn_readfirstlane(lo);   // R4 lesson: pin scalarness
    int fill = bucketCnt[b];
    int rel0 = u - slotStart[b];
    if (rel0 >= fill) return;        // wave wholly in bucket padding
    int k = b / N_C;                 // wave-uniform branch id -> s_load weights

    int L = threadIdx.x;
    int quad = L >> 4, col = L & 15;
    int slot = u + L;                // own slot: coalesced payload read + fbuf store
    bool valid = (rel0 + L) < fill;

    uint4 pl = payload[slot];
    int s = (int)(pl.x & 0xFFFFu);
    int d = (int)(pl.x >> 16);
    _Float16 wh = __builtin_bit_cast(_Float16, (unsigned short)(pl.y >> 16));

    // ---- stage m (f16, zero-padded k=36..63): packed half8 subtract ----
    const uint4* xj = ((const uint4*)xh) + 4 * (size_t)s;   // 64B f16 row
    const uint4* xi = ((const uint4*)xh) + 4 * (size_t)d;
    uint4* mrow = (uint4*)(mreg + L * 144);
#pragma unroll
    for (int q = 0; q < 4; ++q) {
        half8 a8 = __builtin_bit_cast(half8, xj[q]);
        half8 b8 = __builtin_bit_cast(half8, xi[q]);
        half8 d8 = a8 - b8;
        mrow[q] = __builtin_bit_cast(uint4, d8);
    }
    mrow[4] = make_uint4(pl.z, pl.w, 0u, 0u);
    mrow[5] = make_uint4(0u, 0u, 0u, 0u);
    mrow[6] = make_uint4(0u, 0u, 0u, 0u);
    mrow[7] = make_uint4(0u, 0u, 0u, 0u);

    // ---- B fragments (VGPR-resident; coalesced 16B/lane loads) ----
    half8 B1[2][2], B2[2];
#pragma unroll
    for (int kt = 0; kt < 2; ++kt)
#pragma unroll
        for (int nt = 0; nt < 2; ++nt)
            B1[kt][nt] = __builtin_bit_cast(half8, w1f4[((k * 2 + kt) * 2 + nt) * 64 + L]);
#pragma unroll
    for (int nt = 0; nt < 2; ++nt)
        B2[nt] = __builtin_bit_cast(half8, w2f4[(k * 2 + nt) * 64 + L]);
    float b1o0 = b1[k * 32 + col],      b1o1 = b1[k * 32 + 16 + col];
    float b2o0 = b2[k * 32 + col],      b2o1 = b2[k * 32 + 16 + col];

#pragma unroll
    for (int mt = 0; mt < 4; ++mt) {
        int arow = mt * 16 + col;
        half8 a0 = __builtin_bit_cast(half8, *(const uint4*)(mreg + arow * 144 + quad * 16));
        half8 a1 = __builtin_bit_cast(half8, *(const uint4*)(mreg + arow * 144 + 64 + quad * 16));
        f32x4 c0 = {b1o0, b1o0, b1o0, b1o0};
        f32x4 c1 = {b1o1, b1o1, b1o1, b1o1};
        c0 = MFMA(a0, B1[0][0], c0);
        c0 = MFMA(a1, B1[1][0], c0);
        c1 = MFMA(a0, B1[0][1], c1);
        c1 = MFMA(a1, B1[1][1], c1);
#pragma unroll
        for (int r = 0; r < 4; ++r) {
            int er = quad * 4 + r;
            *(unsigned short*)(hreg + er * 80 + col * 2) =
                __builtin_bit_cast(unsigned short, (_Float16)fmaxf(c0[r], 0.0f));
            *(unsigned short*)(hreg + er * 80 + (16 + col) * 2) =
                __builtin_bit_cast(unsigned short, (_Float16)fmaxf(c1[r], 0.0f));
        }
        half8 ah = __builtin_bit_cast(half8, *(const uint4*)(hreg + col * 80 + quad * 16));
        f32x4 d0 = {b2o0, b2o0, b2o0, b2o0};
        f32x4 d1 = {b2o1, b2o1, b2o1, b2o1};
        d0 = MFMA(ah, B2[0], d0);
        d1 = MFMA(ah, B2[1], d1);
#pragma unroll
        for (int r = 0; r < 4; ++r) {
            int edge = mt * 16 + quad * 4 + r;
            *(unsigned short*)(mreg + edge * 144 + col * 2) =
                __builtin_bit_cast(unsigned short, (_Float16)fmaxf(d0[r], 0.0f));
            *(unsigned short*)(mreg + edge * 144 + (16 + col) * 2) =
                __builtin_bit_cast(unsigned short, (_Float16)fmaxf(d1[r], 0.0f));
        }
    }

    // ---- read back own edge's row, *w (packed f16), coalesced 64B store ----
    half8 w8 = {wh, wh, wh, wh, wh, wh, wh, wh};
    uint4* orow = (uint4*)(mreg + L * 144);
    uint4* frow = (uint4*)(fbuf + 32 * (size_t)slot);
#pragma unroll
    for (int q = 0; q < 4; ++q) {
        half8 v8 = __builtin_bit_cast(half8, orow[q]);
        v8 = v8 * w8;
        if (valid) frow[q] = __builtin_bit_cast(uint4, v8);
    }
}

// Binned aggregation: one block per 256-node bin; LDS f32 accumulator 32KB +
// LDS degree counts; streams the 8 branch-segments of this bin; fused
// mean + bias + skip GEMM. No CSR, no global deg, no scan.
__global__ void __launch_bounds__(1024) agg_kernel(
    const unsigned short* __restrict__ fbuf, const uint4* __restrict__ payload,
    const int* __restrict__ slotStart, const int* __restrict__ bucketCnt,
    const float* __restrict__ x, const float* __restrict__ Wr,
    const float* __restrict__ br, float* __restrict__ out) {
    __shared__ float acc[8192];
    __shared__ int cntN[256];
    int t = threadIdx.x, c = blockIdx.x;
    for (int j = t; j < 8192; j += 1024) acc[j] = 0.0f;
    if (t < 256) cntN[t] = 0;
    __syncthreads();
    int r8 = t >> 3, lane = t & 7;
    for (int k = 0; k < K_BR; ++k) {
        int b = k * N_C + c;
        int st = slotStart[b], rows = bucketCnt[b];
        for (int base = 0; base < rows; base += 128) {
            int r = base + r8;
            if (r < rows) {
                int slot = st + r;
                int n = (int)(payload[slot].x >> 16) & 255;
                uint2 v = ((const uint2*)fbuf)[(size_t)slot * 8 + lane];
                h2 p01 = __builtin_bit_cast(h2, v.x);
                h2 p23 = __builtin_bit_cast(h2, v.y);
                int ch = lane * 4;
                atomicAdd(&acc[n * 32 + ch + 0], (float)p01.x);
                atomicAdd(&acc[n * 32 + ch + 1], (float)p01.y);
                atomicAdd(&acc[n * 32 + ch + 2], (float)p23.x);
                atomicAdd(&acc[n * 32 + ch + 3], (float)p23.y);
                if (lane == 0) atomicAdd(&cntN[n], 1);
            }
        }
    }
    __syncthreads();
    for (int j = t; j < 8192; j += 1024) {
        int n = j >> 5, ch = j & 31;
        int g = c * 256 + n;
        if (g < N_NODES) {
            float a = acc[j] / (float)max(cntN[n], 1) + br[ch];
            const float* xr = x + 32 * (size_t)g;
#pragma unroll
            for (int cc = 0; cc < 32; ++cc) a = fmaf(xr[cc], Wr[cc * 32 + ch], a);
            out[(size_t)g * 32 + ch] = a;
        }
    }
}

extern "C" void kernel_launch(void* const* d_in, const int* in_sizes, int n_in,
                              void* d_out, int out_size, void* d_ws, size_t ws_size,
                              hipStream_t stream) {
    const float* x   = (const float*)d_in[0];
    const float* pos = (const float*)d_in[1];
    const int*   ei  = (const int*)d_in[2];
    const float* ea  = (const float*)d_in[3];
    const float* ew  = (const float*)d_in[4];
    const float* W1  = (const float*)d_in[5];
    const float* b1  = (const float*)d_in[6];
    const float* W2  = (const float*)d_in[7];
    const float* b2  = (const float*)d_in[8];
    const float* Wr  = (const float*)d_in[9];
    const float* br  = (const float*)d_in[10];
    float* out = (float*)d_out;

    char* ws = (char*)d_ws;
    unsigned short* fbuf   = (unsigned short*)(ws + 0);
    uint4* payload         = (uint4*)(ws + 57524224);
    unsigned* xh           = (unsigned*)(ws + 71905280);
    unsigned short* kcArr  = (unsigned short*)(ws + 75105280);
    int* bucketCnt         = (int*)(ws + 76705280);
    int* bucketCur         = (int*)(ws + 76711552);
    int* slotStart         = (int*)(ws + 76717824);
    uint4* w1f4            = (uint4*)(ws + 76724224);
    uint4* w2f4            = (uint4*)(ws + 76756992);

    hipMemsetAsync(bucketCnt, 0, 12544, stream);   // bucketCnt + bucketCur

    hist_kernel<<<FATB, 1024, 0, stream>>>(ei, pos, x, bucketCnt, kcArr, xh);
    tiny_kernel<<<1, 1024, 0, stream>>>(bucketCnt, slotStart, W1, W2, w1f4, w2f4);
    scatter_kernel<<<FATB, 1024, 0, stream>>>(ei, ea, ew, kcArr, slotStart,
                                              bucketCur, payload);
    mlp_kernel<<<MLP_WAVES, 64, 0, stream>>>(payload, xh, w1f4, b1, w2f4, b2,
                                             slotStart, bucketCnt, fbuf);
    agg_kernel<<<N_C, 1024, 0, stream>>>(fbuf, payload, slotStart, bucketCnt,
                                         x, Wr, br, out);
}

// Round 18
// 203.389 us; speedup vs baseline: 1.7659x; 1.7659x over previous
//
#include <hip/hip_runtime.h>

#define N_NODES 50000
#define N_EDGES 800000
#define K_BR    8
#define N_C     196              // coarse bin: c = d >> 8  (0..195)
#define N_BUK   1568             // bucket b = k*196 + c  (k-major -> branch-pure)
#define CAP_SLOTS 898816         // >= 800000 + 1568*63, multiple of 64
#define MLP_WAVES (CAP_SLOTS/64) // 14044
#define FATB    98               // fat edge blocks: 98*1024*8 = 802816 >= 800000

typedef _Float16 h2 __attribute__((ext_vector_type(2)));
typedef _Float16 half8 __attribute__((ext_vector_type(8)));
typedef float f32x4 __attribute__((ext_vector_type(4)));

#define MFMA(a, b, c) __builtin_amdgcn_mfma_f32_16x16x32_f16((a), (b), (c), 0, 0, 0)

// ---------------- workspace layout (bytes) ----------------
// fbuf      : 800,000 x 64 B f16 (dense) @ 0           (51,200,000)
// payload   : CAP_SLOTS x 16 B           @ 51,200,000  (14,381,056)
// xh        : 50,000 x 32 f16            @ 65,581,056  (3,200,000)
// kcArr     : E u16 (bucket per edge)    @ 68,781,056  (1,600,000)
// bucketCnt : 1568 ints                  @ 70,381,056  (6,272)  [memset 0]
// bucketCur : 1568 ints                  @ 70,387,328  (6,272)  [memset 0]
// slotStart : 1569 ints                  @ 70,393,600  (6,276)
// binStart  : 197 ints                   @ 70,399,876  (788)
// nodeStartG: N ints                     @ 70,400,664  (200,000)
// degG      : N ints                     @ 70,600,664  (200,000)
// slotOf    : CAP_SLOTS ints             @ 70,800,664  (3,595,264)
// w1f4      : 2048 uint4 (B-frags L1)    @ 74,395,936  (32,768)
// w2f4      : 1024 uint4 (B-frags L2)    @ 74,428,704  (16,384)
// total: 74,445,088  (< proven ws floor 109,473,920)

__device__ __forceinline__ int branch_idx(float dx, float dy) {
    return (dx > 0.0f ? 1 : 0) + (dy > 0.0f ? 2 : 0) +
           ((fabsf(dx) - fabsf(dy)) > 0.0f ? 4 : 0);
}

__device__ __forceinline__ unsigned pk_f16pair(float a, float b) {
    h2 p; p.x = (_Float16)a; p.y = (_Float16)b;
    return __builtin_bit_cast(unsigned, p);
}

__device__ __forceinline__ unsigned short f16bits(float a) {
    _Float16 h = (_Float16)a;
    return __builtin_bit_cast(unsigned short, h);
}

// Fat histogram pass: LDS 1568-bin hist -> ~153K global atomics total (vs the
// 800K per-edge atomics whose ~15-19K/us device floor capped R14-16 at 53us).
// Also emits bucket id per edge + f16 x-mirror.
__global__ void __launch_bounds__(1024) hist_kernel(
    const int* __restrict__ ei, const float* __restrict__ pos,
    const float* __restrict__ x,
    int* __restrict__ bucketCnt, unsigned short* __restrict__ kcArr,
    unsigned* __restrict__ xh) {
    __shared__ int h[N_BUK];
    int t = threadIdx.x;
    for (int j = t; j < N_BUK; j += 1024) h[j] = 0;
    __syncthreads();
#pragma unroll
    for (int i = 0; i < 8; ++i) {
        int e = blockIdx.x * 8192 + i * 1024 + t;
        if (e < N_EDGES) {
            int s = ei[e], d = ei[N_EDGES + e];
            float2 ps = ((const float2*)pos)[s];
            float2 pd = ((const float2*)pos)[d];
            int k = branch_idx(ps.x - pd.x, ps.y - pd.y);
            int b = k * N_C + (d >> 8);
            atomicAdd(&h[b], 1);
            kcArr[e] = (unsigned short)b;
            float2 xv = ((const float2*)x)[e];   // e covers 800000 float2 = all of x
            xh[e] = pk_f16pair(xv.x, xv.y);
        }
    }
    __syncthreads();
    for (int j = t; j < N_BUK; j += 1024) {
        int c = h[j];
        if (c) atomicAdd(&bucketCnt[j], c);
    }
}

// (1) 64-aligned exclusive scan of bucketCnt -> slotStart (mlp wave purity);
// (2) exact per-bin scan -> binStart (dense fbuf space);
// (3) W1/W2 MFMA B-frag packing (B[k=quad*8+j][n=lane&15], m120 layout).
__global__ void __launch_bounds__(1024) tiny_kernel(
    const int* __restrict__ bucketCnt, int* __restrict__ slotStart,
    int* __restrict__ binStart,
    const float* __restrict__ W1, const float* __restrict__ W2,
    uint4* __restrict__ w1f4, uint4* __restrict__ w2f4) {
    __shared__ int sc[1024];
    __shared__ int sb[256];
    int t = threadIdx.x;
    int b0 = 2 * t, b1 = 2 * t + 1;
    int a0 = (b0 < N_BUK) ? ((bucketCnt[b0] + 63) & ~63) : 0;
    int a1 = (b1 < N_BUK) ? ((bucketCnt[b1] + 63) & ~63) : 0;
    sc[t] = a0 + a1;
    __syncthreads();
    for (int off = 1; off < 1024; off <<= 1) {
        int tmp = (t >= off) ? sc[t - off] : 0;
        __syncthreads();
        sc[t] += tmp;
        __syncthreads();
    }
    int excl = sc[t] - (a0 + a1);
    if (b0 < N_BUK) slotStart[b0] = excl;
    if (b1 < N_BUK) slotStart[b1] = excl + a0;
    if (t == 1023) slotStart[N_BUK] = sc[1023];

    // per-bin exact scan
    int v = 0;
    if (t < N_C) {
#pragma unroll
        for (int k = 0; k < K_BR; ++k) v += bucketCnt[k * N_C + t];
    }
    if (t < 256) sb[t] = v;
    __syncthreads();
    for (int off = 1; off < 256; off <<= 1) {
        int tmp = (t < 256 && t >= off) ? sb[t - off] : 0;
        __syncthreads();
        if (t < 256) sb[t] += tmp;
        __syncthreads();
    }
    if (t < N_C) binStart[t] = sb[t] - v;
    if (t == 255) binStart[N_C] = sb[255];

    for (int idx = t; idx < 3072; idx += 1024) {
        if (idx < 2048) {                         // layer-1 B frags
            int L = idx & 63, fl = idx >> 6;
            int nt = fl & 1, kt = (fl >> 1) & 1, kk = fl >> 2;
            int quad = L >> 4, col = L & 15;
            unsigned dw[4];
#pragma unroll
            for (int i = 0; i < 4; ++i) {
                float v0 = 0.0f, v1 = 0.0f;
                int k0 = kt * 32 + quad * 8 + 2 * i;
                if (k0 < 36)     v0 = W1[kk * 1152 + k0 * 32 + nt * 16 + col];
                if (k0 + 1 < 36) v1 = W1[kk * 1152 + (k0 + 1) * 32 + nt * 16 + col];
                dw[i] = pk_f16pair(v0, v1);
            }
            w1f4[idx] = make_uint4(dw[0], dw[1], dw[2], dw[3]);
        } else {                                  // layer-2 B frags
            int u2 = idx - 2048;
            int L = u2 & 63, fl = u2 >> 6;
            int nt = fl & 1, kk = fl >> 1;
            int quad = L >> 4, col = L & 15;
            unsigned dw[4];
#pragma unroll
            for (int i = 0; i < 4; ++i) {
                int k0 = quad * 8 + 2 * i;
                dw[i] = pk_f16pair(W2[kk * 1024 + k0 * 32 + nt * 16 + col],
                                   W2[kk * 1024 + (k0 + 1) * 32 + nt * 16 + col]);
            }
            w2f4[u2] = make_uint4(dw[0], dw[1], dw[2], dw[3]);
        }
    }
}

// Fat scatter: stash 8 edges in VGPRs, LDS ranks, claim per-bucket block base
// (~153K global atomics total), write 16B payloads bucket-dense.
__global__ void __launch_bounds__(1024) scatter_kernel(
    const int* __restrict__ ei, const float* __restrict__ ea,
    const float* __restrict__ ew, const unsigned short* __restrict__ kcArr,
    const int* __restrict__ slotStart, int* __restrict__ bucketCur,
    uint4* __restrict__ payload) {
    __shared__ int h[N_BUK];
    __shared__ int base[N_BUK];
    int t = threadIdx.x;
    for (int j = t; j < N_BUK; j += 1024) h[j] = 0;
    __syncthreads();
    unsigned sd[8], brk[8], e01[8], e23[8], ewh[8];
#pragma unroll
    for (int i = 0; i < 8; ++i) {
        int e = blockIdx.x * 8192 + i * 1024 + t;
        bool v = e < N_EDGES;
        int b = 0, rk = 0;
        if (v) {
            int s = ei[e], d = ei[N_EDGES + e];
            sd[i] = (unsigned)s | ((unsigned)d << 16);
            b = kcArr[e];
            rk = atomicAdd(&h[b], 1);
            float4 eav = ((const float4*)ea)[e];
            e01[i] = pk_f16pair(eav.x, eav.y);
            e23[i] = pk_f16pair(eav.z, eav.w);
            ewh[i] = (unsigned)f16bits(ew[e]);
        }
        brk[i] = (unsigned)b | ((unsigned)rk << 16) | (v ? 0x80000000u : 0u);
    }
    __syncthreads();
    for (int j = t; j < N_BUK; j += 1024) {
        int c = h[j];
        base[j] = c ? atomicAdd(&bucketCur[j], c) : 0;
    }
    __syncthreads();
#pragma unroll
    for (int i = 0; i < 8; ++i) {
        if (brk[i] & 0x80000000u) {
            int b = (int)(brk[i] & 0xFFFFu);
            int rk = (int)((brk[i] >> 16) & 0x7FFFu);
            int slot = slotStart[b] + base[b] + rk;
            payload[slot] = make_uint4(sd[i], ewh[i] << 16, e01[i], e23[i]);
        }
    }
}

// Per-bin node sort: one block per 256-node bin. LDS histogram-scale int
// atomics (~4K/block — R17 lesson: LDS atomics die at ~131K/block, fine here).
// Emits slotOf (node-sorted fbuf slot per payload slot), nodeStartG, degG.
__global__ void __launch_bounds__(1024) binsort_kernel(
    const uint4* __restrict__ payload, const int* __restrict__ slotStart,
    const int* __restrict__ bucketCnt, const int* __restrict__ binStart,
    int* __restrict__ slotOf, int* __restrict__ nodeStartG, int* __restrict__ degG) {
    __shared__ int cntA[256], cntB[256], startL[256], scn[256];
    int t = threadIdx.x, c = blockIdx.x;
    if (t < 256) { cntA[t] = 0; cntB[t] = 0; }
    __syncthreads();
    const unsigned* p32 = (const unsigned*)payload;
    for (int k = 0; k < K_BR; ++k) {
        int b = k * N_C + c, st = slotStart[b], rows = bucketCnt[b];
        for (int r = t; r < rows; r += 1024) {
            int n = (int)((p32[4 * (size_t)(st + r)] >> 16) & 255u);
            atomicAdd(&cntA[n], 1);
        }
    }
    __syncthreads();
    int v = (t < 256) ? cntA[t] : 0;
    if (t < 256) scn[t] = v;
    __syncthreads();
    for (int off = 1; off < 256; off <<= 1) {
        int tmp = (t < 256 && t >= off) ? scn[t - off] : 0;
        __syncthreads();
        if (t < 256) scn[t] += tmp;
        __syncthreads();
    }
    if (t < 256) startL[t] = scn[t] - v;
    __syncthreads();
    int bb = binStart[c];
    if (t < 256) {
        int g = c * 256 + t;
        if (g < N_NODES) { nodeStartG[g] = bb + startL[t]; degG[g] = v; }
    }
    for (int k = 0; k < K_BR; ++k) {
        int b = k * N_C + c, st = slotStart[b], rows = bucketCnt[b];
        for (int r = t; r < rows; r += 1024) {
            int slot = st + r;
            int n = (int)((p32[4 * (size_t)slot] >> 16) & 255u);
            int rk = atomicAdd(&cntB[n], 1);
            slotOf[slot] = bb + startL[n] + rk;
        }
    }
}

// MFMA MLP (R12-verified layouts, R14 64-thr single-wave blocks, R17 wave-
// uniform binary-search bucket id). R18: fbuf store at slotOf[slot] — node-
// sorted, bin-local 64B scatter (R13/R14-proven pattern); payload read own
// slot, coalesced.
__global__ void __launch_bounds__(64) mlp_kernel(
    const uint4* __restrict__ payload,
    const unsigned* __restrict__ xh,
    const uint4* __restrict__ w1f4, const float* __restrict__ b1,
    const uint4* __restrict__ w2f4, const float* __restrict__ b2,
    const int* __restrict__ slotStart, const int* __restrict__ bucketCnt,
    const int* __restrict__ slotOf,
    unsigned short* __restrict__ fbuf) {
    __shared__ uint4 lds4[656];   // m 64x144B + h 16x80B = 10,496 B
    char* mreg = (char*)lds4;
    char* hreg = mreg + 9216;

    int u = __builtin_amdgcn_readfirstlane((int)blockIdx.x * 64);
    if (u >= slotStart[N_BUK]) return;
    int lo = 0;
#pragma unroll
    for (int st = 1024; st; st >>= 1) {
        int cand = lo + st;
        if (cand < N_BUK && slotStart[cand] <= u) lo = cand;
    }
    int b = __builtin_amdgcn_readfirstlane(lo);   // R4 lesson: pin scalarness
    int fill = bucketCnt[b];
    int rel0 = u - slotStart[b];
    if (rel0 >= fill) return;        // wave wholly in bucket padding
    int k = b / N_C;                 // wave-uniform branch id -> s_load weights

    int L = threadIdx.x;
    int quad = L >> 4, col = L & 15;
    int slot = u + L;                // own slot: coalesced payload/slotOf reads
    bool valid = (rel0 + L) < fill;

    uint4 pl = payload[slot];
    int so = slotOf[slot];           // node-sorted fbuf destination
    int s = (int)(pl.x & 0xFFFFu);
    int d = (int)(pl.x >> 16);
    _Float16 wh = __builtin_bit_cast(_Float16, (unsigned short)(pl.y >> 16));

    // ---- stage m (f16, zero-padded k=36..63): packed half8 subtract ----
    const uint4* xj = ((const uint4*)xh) + 4 * (size_t)s;   // 64B f16 row
    const uint4* xi = ((const uint4*)xh) + 4 * (size_t)d;
    uint4* mrow = (uint4*)(mreg + L * 144);
#pragma unroll
    for (int q = 0; q < 4; ++q) {
        half8 a8 = __builtin_bit_cast(half8, xj[q]);
        half8 b8 = __builtin_bit_cast(half8, xi[q]);
        half8 d8 = a8 - b8;
        mrow[q] = __builtin_bit_cast(uint4, d8);
    }
    mrow[4] = make_uint4(pl.z, pl.w, 0u, 0u);
    mrow[5] = make_uint4(0u, 0u, 0u, 0u);
    mrow[6] = make_uint4(0u, 0u, 0u, 0u);
    mrow[7] = make_uint4(0u, 0u, 0u, 0u);

    // ---- B fragments (VGPR-resident; coalesced 16B/lane loads) ----
    half8 B1[2][2], B2[2];
#pragma unroll
    for (int kt = 0; kt < 2; ++kt)
#pragma unroll
        for (int nt = 0; nt < 2; ++nt)
            B1[kt][nt] = __builtin_bit_cast(half8, w1f4[((k * 2 + kt) * 2 + nt) * 64 + L]);
#pragma unroll
    for (int nt = 0; nt < 2; ++nt)
        B2[nt] = __builtin_bit_cast(half8, w2f4[(k * 2 + nt) * 64 + L]);
    float b1o0 = b1[k * 32 + col],      b1o1 = b1[k * 32 + 16 + col];
    float b2o0 = b2[k * 32 + col],      b2o1 = b2[k * 32 + 16 + col];

#pragma unroll
    for (int mt = 0; mt < 4; ++mt) {
        int arow = mt * 16 + col;
        half8 a0 = __builtin_bit_cast(half8, *(const uint4*)(mreg + arow * 144 + quad * 16));
        half8 a1 = __builtin_bit_cast(half8, *(const uint4*)(mreg + arow * 144 + 64 + quad * 16));
        f32x4 c0 = {b1o0, b1o0, b1o0, b1o0};
        f32x4 c1 = {b1o1, b1o1, b1o1, b1o1};
        c0 = MFMA(a0, B1[0][0], c0);
        c0 = MFMA(a1, B1[1][0], c0);
        c1 = MFMA(a0, B1[0][1], c1);
        c1 = MFMA(a1, B1[1][1], c1);
#pragma unroll
        for (int r = 0; r < 4; ++r) {
            int er = quad * 4 + r;
            *(unsigned short*)(hreg + er * 80 + col * 2) =
                __builtin_bit_cast(unsigned short, (_Float16)fmaxf(c0[r], 0.0f));
            *(unsigned short*)(hreg + er * 80 + (16 + col) * 2) =
                __builtin_bit_cast(unsigned short, (_Float16)fmaxf(c1[r], 0.0f));
        }
        half8 ah = __builtin_bit_cast(half8, *(const uint4*)(hreg + col * 80 + quad * 16));
        f32x4 d0 = {b2o0, b2o0, b2o0, b2o0};
        f32x4 d1 = {b2o1, b2o1, b2o1, b2o1};
        d0 = MFMA(ah, B2[0], d0);
        d1 = MFMA(ah, B2[1], d1);
#pragma unroll
        for (int r = 0; r < 4; ++r) {
            int edge = mt * 16 + quad * 4 + r;
            *(unsigned short*)(mreg + edge * 144 + col * 2) =
                __builtin_bit_cast(unsigned short, (_Float16)fmaxf(d0[r], 0.0f));
            *(unsigned short*)(mreg + edge * 144 + (16 + col) * 2) =
                __builtin_bit_cast(unsigned short, (_Float16)fmaxf(d1[r], 0.0f));
        }
    }

    // ---- read back own edge's row, *w (packed f16), 64B store at slotOf ----
    half8 w8 = {wh, wh, wh, wh, wh, wh, wh, wh};
    uint4* orow = (uint4*)(mreg + L * 144);
    uint4* frow = (uint4*)(fbuf + 32 * (size_t)so);
#pragma unroll
    for (int q = 0; q < 4; ++q) {
        half8 v8 = __builtin_bit_cast(half8, orow[q]);
        v8 = v8 * w8;
        if (valid) frow[q] = __builtin_bit_cast(uint4, v8);
    }
}

// CSR streaming agg (R14-proven): 4 channels/thread, uint2 reads, no atomics.
__global__ void agg_kernel(const unsigned short* __restrict__ fbuf,
                           const int* __restrict__ nodeStartG, const int* __restrict__ degG,
                           const float* __restrict__ x, const float* __restrict__ Wr,
                           const float* __restrict__ br, float* __restrict__ out) {
    int t = blockIdx.x * blockDim.x + threadIdx.x;
    if (t >= N_NODES * 8) return;
    int n = t >> 3, g8 = t & 7;          // channels 4*g8 .. 4*g8+3
    int st = nodeStartG[n], dg = degG[n];
    const uint2* fb = (const uint2*)fbuf;
    float a0 = 0.0f, a1 = 0.0f, a2 = 0.0f, a3 = 0.0f;
    for (int j = 0; j < dg; ++j) {
        uint2 uu = fb[(size_t)(st + j) * 8 + g8];   // node-contiguous stream
        h2 p01 = __builtin_bit_cast(h2, uu.x);
        h2 p23 = __builtin_bit_cast(h2, uu.y);
        a0 += (float)p01.x;
        a1 += (float)p01.y;
        a2 += (float)p23.x;
        a3 += (float)p23.y;
    }
    float inv = 1.0f / (float)max(dg, 1);
    int o = g8 * 4;
    a0 = a0 * inv + br[o];
    a1 = a1 * inv + br[o + 1];
    a2 = a2 * inv + br[o + 2];
    a3 = a3 * inv + br[o + 3];
    const float* xr = x + 32 * (size_t)n;
#pragma unroll
    for (int c = 0; c < 32; ++c) {
        float xv = xr[c];
        a0 = fmaf(xv, Wr[c * 32 + o], a0);
        a1 = fmaf(xv, Wr[c * 32 + o + 1], a1);
        a2 = fmaf(xv, Wr[c * 32 + o + 2], a2);
        a3 = fmaf(xv, Wr[c * 32 + o + 3], a3);
    }
    float4* o4 = (float4*)(out + 32 * (size_t)n + o);
    *o4 = make_float4(a0, a1, a2, a3);
}

extern "C" void kernel_launch(void* const* d_in, const int* in_sizes, int n_in,
                              void* d_out, int out_size, void* d_ws, size_t ws_size,
                              hipStream_t stream) {
    const float* x   = (const float*)d_in[0];
    const float* pos = (const float*)d_in[1];
    const int*   ei  = (const int*)d_in[2];
    const float* ea  = (const float*)d_in[3];
    const float* ew  = (const float*)d_in[4];
    const float* W1  = (const float*)d_in[5];
    const float* b1  = (const float*)d_in[6];
    const float* W2  = (const float*)d_in[7];
    const float* b2  = (const float*)d_in[8];
    const float* Wr  = (const float*)d_in[9];
    const float* br  = (const float*)d_in[10];
    float* out = (float*)d_out;

    char* ws = (char*)d_ws;
    unsigned short* fbuf   = (unsigned short*)(ws + 0);
    uint4* payload         = (uint4*)(ws + 51200000);
    unsigned* xh           = (unsigned*)(ws + 65581056);
    unsigned short* kcArr  = (unsigned short*)(ws + 68781056);
    int* bucketCnt         = (int*)(ws + 70381056);
    int* bucketCur         = (int*)(ws + 70387328);
    int* slotStart         = (int*)(ws + 70393600);
    int* binStart          = (int*)(ws + 70399876);
    int* nodeStartG        = (int*)(ws + 70400664);
    int* degG              = (int*)(ws + 70600664);
    int* slotOf            = (int*)(ws + 70800664);
    uint4* w1f4            = (uint4*)(ws + 74395936);
    uint4* w2f4            = (uint4*)(ws + 74428704);

    hipMemsetAsync(bucketCnt, 0, 12544, stream);   // bucketCnt + bucketCur

    hist_kernel<<<FATB, 1024, 0, stream>>>(ei, pos, x, bucketCnt, kcArr, xh);
    tiny_kernel<<<1, 1024, 0, stream>>>(bucketCnt, slotStart, binStart, W1, W2, w1f4, w2f4);
    scatter_kernel<<<FATB, 1024, 0, stream>>>(ei, ea, ew, kcArr, slotStart,
                                              bucketCur, payload);
    binsort_kernel<<<N_C, 1024, 0, stream>>>(payload, slotStart, bucketCnt, binStart,
                                             slotOf, nodeStartG, degG);
    mlp_kernel<<<MLP_WAVES, 64, 0, stream>>>(payload, xh, w1f4, b1, w2f4, b2,
                                             slotStart, bucketCnt, slotOf, fbuf);
    agg_kernel<<<(N_NODES * 8 + 255) / 256, 256, 0, stream>>>(fbuf, nodeStartG, degG,
                                                              x, Wr, br, out);
}